// Round 1
// baseline (431.987 us; speedup 1.0000x reference)
//
#include <hip/hip_runtime.h>

typedef __attribute__((ext_vector_type(8))) short bf16x8;
typedef __attribute__((ext_vector_type(4))) float f32x4;

__device__ __forceinline__ float bf2f(unsigned short u) {
  union { unsigned int i; float f; } v;
  v.i = ((unsigned int)u) << 16;
  return v.f;
}
__device__ __forceinline__ unsigned short f2bf(float f) {
  union { float f; unsigned int i; } v;
  v.f = f;
  unsigned int r = v.i + 0x7FFFu + ((v.i >> 16) & 1u);  // RNE
  return (unsigned short)(r >> 16);
}

// ---------------- fp32 -> bf16 convert (4 elems/thread) ----------------
__global__ __launch_bounds__(256) void cvt_f32_bf16(
    const float* __restrict__ in, unsigned short* __restrict__ out, int n4) {
  int i = blockIdx.x * 256 + threadIdx.x;
  if (i >= n4) return;
  float4 v = ((const float4*)in)[i];
  ushort4 o;
  o.x = f2bf(v.x);
  o.y = f2bf(v.y);
  o.z = f2bf(v.z);
  o.w = f2bf(v.w);
  ((ushort4*)out)[i] = o;
}

// ---------------- GEMM: C[M,N] = A[M,K] @ Bt[N,K]^T + bias ----------------
// bf16 inputs (both K-contiguous), fp32 accumulate. 128x128 block tile,
// BK=64, 4 waves in 2x2, each wave 64x64 via 4x4 of 16x16x32 MFMA.
// LDS stride 72 shorts (144B): lanes m and m+8 share a bank -> 2-way (free).
template <bool OUTF32>
__global__ __launch_bounds__(256) void gemm_bt(
    const unsigned short* __restrict__ A, const unsigned short* __restrict__ Bt,
    const float* __restrict__ bias, void* __restrict__ Cout, int N, int K) {
  __shared__ unsigned short lA[128 * 72];
  __shared__ unsigned short lB[128 * 72];
  const int tid = threadIdx.x;
  const int lane = tid & 63;
  const int w = tid >> 6;
  const int wm = w >> 1, wn = w & 1;
  const long mb = (long)blockIdx.x * 128;
  const long nb = (long)blockIdx.y * 128;
  f32x4 acc[4][4];
#pragma unroll
  for (int i = 0; i < 4; i++)
#pragma unroll
    for (int j = 0; j < 4; j++) acc[i][j] = (f32x4){0.f, 0.f, 0.f, 0.f};

  for (int kb = 0; kb < K; kb += 64) {
    __syncthreads();
#pragma unroll
    for (int c = tid; c < 1024; c += 256) {
      int row = c >> 3, k8 = (c & 7) << 3;
      *(uint4*)&lA[row * 72 + k8] = *(const uint4*)(A + (mb + row) * K + kb + k8);
      *(uint4*)&lB[row * 72 + k8] = *(const uint4*)(Bt + (nb + row) * K + kb + k8);
    }
    __syncthreads();
#pragma unroll
    for (int ks = 0; ks < 64; ks += 32) {
      int kq = ks + (lane >> 4) * 8;
      bf16x8 af[4], bfr[4];
#pragma unroll
      for (int i = 0; i < 4; i++)
        af[i] = *(const bf16x8*)&lA[(wm * 64 + i * 16 + (lane & 15)) * 72 + kq];
#pragma unroll
      for (int j = 0; j < 4; j++)
        bfr[j] = *(const bf16x8*)&lB[(wn * 64 + j * 16 + (lane & 15)) * 72 + kq];
#pragma unroll
      for (int i = 0; i < 4; i++)
#pragma unroll
        for (int j = 0; j < 4; j++)
          acc[i][j] =
              __builtin_amdgcn_mfma_f32_16x16x32_bf16(af[i], bfr[j], acc[i][j], 0, 0, 0);
    }
  }
  // C/D layout: col = lane&15, row = (lane>>4)*4 + r   [verified m89]
#pragma unroll
  for (int i = 0; i < 4; i++) {
    long row0 = mb + wm * 64 + i * 16 + (lane >> 4) * 4;
#pragma unroll
    for (int j = 0; j < 4; j++) {
      long col = nb + wn * 64 + j * 16 + (lane & 15);
      float bb = bias[col];
#pragma unroll
      for (int r = 0; r < 4; r++) {
        float val = acc[i][j][r] + bb;
        if (OUTF32)
          ((float*)Cout)[(row0 + r) * N + col] = val;
        else
          ((unsigned short*)Cout)[(row0 + r) * N + col] = f2bf(val);
      }
    }
  }
}

// ---------------- per-(row,head) L2 normalize, one wave each ----------------
__global__ __launch_bounds__(256) void l2norm_heads(const unsigned short* in,
                                                    unsigned short* out) {
  int wg = blockIdx.x * 4 + (threadIdx.x >> 6);  // row-head id, 131072 total
  int lane = threadIdx.x & 63;
  long base = (long)(wg >> 3) * 512 + (wg & 7) * 64;
  float v = bf2f(in[base + lane]);
  float s = v * v;
  s += __shfl_xor(s, 1);
  s += __shfl_xor(s, 2);
  s += __shfl_xor(s, 4);
  s += __shfl_xor(s, 8);
  s += __shfl_xor(s, 16);
  s += __shfl_xor(s, 32);
  float inv = 1.0f / fmaxf(sqrtf(s), 1e-12f);
  out[base + lane] = f2bf(v * inv);
}

// ---------------- cosine attention, no-max online softmax ----------------
// Block: (q-tile of 128, group g=(bm,h)). 4 waves x 32 q-rows. K-tile = 64.
// Scores in [-1,1] -> exp() directly, running row-sum only.
__global__ __launch_bounds__(256) void attn_cos(
    const unsigned short* __restrict__ Qn, const unsigned short* __restrict__ Kn,
    const unsigned short* __restrict__ V, unsigned short* __restrict__ ctx) {
  __shared__ unsigned short lQ[128 * 72];  // [q][d]
  __shared__ unsigned short lK[64 * 72];   // [k][d]
  __shared__ unsigned short lV[64 * 72];   // transposed: [d][k]
  __shared__ unsigned short lP[128 * 72];  // per-wave private 32 rows: [q][k]
  const int qt = blockIdx.x;  // 0..15
  const int g = blockIdx.y;   // 0..63
  const int bm = g >> 3;
  const int h = g & 7;
  const int tid = threadIdx.x;
  const int lane = tid & 63;
  const int w = tid >> 6;
  const long rowbase = (long)bm * 2048;
  const int colbase = h * 64;

  // stage Q tile [128 x 64]
#pragma unroll
  for (int c = tid; c < 1024; c += 256) {
    int row = c >> 3, d8 = (c & 7) << 3;
    *(uint4*)&lQ[row * 72 + d8] =
        *(const uint4*)(Qn + (rowbase + qt * 128 + row) * 512 + colbase + d8);
  }

  f32x4 cacc[2][4];
#pragma unroll
  for (int i = 0; i < 2; i++)
#pragma unroll
    for (int j = 0; j < 4; j++) cacc[i][j] = (f32x4){0.f, 0.f, 0.f, 0.f};
  float li[2][4] = {{0.f, 0.f, 0.f, 0.f}, {0.f, 0.f, 0.f, 0.f}};

  for (int kt = 0; kt < 32; ++kt) {
    __syncthreads();  // protect lK/lV (and lP) overwrite vs previous iter reads
    // stage K tile [64 x 64]
#pragma unroll
    for (int c = tid; c < 512; c += 256) {
      int row = c >> 3, d8 = (c & 7) << 3;
      *(uint4*)&lK[row * 72 + d8] =
          *(const uint4*)(Kn + (rowbase + kt * 64 + row) * 512 + colbase + d8);
    }
    // stage V transposed: lV[d][k]
    {
      int d8 = (tid & 7) << 3;
#pragma unroll
      for (int i = 0; i < 2; ++i) {
        int kl = i * 32 + (tid >> 3);
        uint4 raw = *(const uint4*)(V + (rowbase + kt * 64 + kl) * 512 + colbase + d8);
        const unsigned short* pr = (const unsigned short*)&raw;
#pragma unroll
        for (int j = 0; j < 8; ++j) lV[(d8 + j) * 72 + kl] = pr[j];
      }
    }
    __syncthreads();

    // S[32q x 64k] = Q . K^T  (d inner, 2 MFMA k-steps)
    f32x4 sacc[2][4];
#pragma unroll
    for (int i = 0; i < 2; i++)
#pragma unroll
      for (int j = 0; j < 4; j++) sacc[i][j] = (f32x4){0.f, 0.f, 0.f, 0.f};
#pragma unroll
    for (int ks = 0; ks < 2; ++ks) {
      int kq = ks * 32 + (lane >> 4) * 8;
      bf16x8 af[2], bfr[4];
#pragma unroll
      for (int i = 0; i < 2; i++)
        af[i] = *(const bf16x8*)&lQ[(w * 32 + i * 16 + (lane & 15)) * 72 + kq];
#pragma unroll
      for (int j = 0; j < 4; j++)
        bfr[j] = *(const bf16x8*)&lK[(j * 16 + (lane & 15)) * 72 + kq];
#pragma unroll
      for (int i = 0; i < 2; i++)
#pragma unroll
        for (int j = 0; j < 4; j++)
          sacc[i][j] =
              __builtin_amdgcn_mfma_f32_16x16x32_bf16(af[i], bfr[j], sacc[i][j], 0, 0, 0);
    }

    // exp, row partial sums, write P (C-layout -> LDS row-major [q][k])
    float part[2][4] = {{0.f, 0.f, 0.f, 0.f}, {0.f, 0.f, 0.f, 0.f}};
#pragma unroll
    for (int i = 0; i < 2; i++)
#pragma unroll
      for (int j = 0; j < 4; j++)
#pragma unroll
        for (int r = 0; r < 4; r++) {
          float p = __expf(sacc[i][j][r]);
          part[i][r] += p;
          lP[(w * 32 + i * 16 + (lane >> 4) * 4 + r) * 72 + j * 16 + (lane & 15)] =
              f2bf(p);
        }
    // reduce row sums across the 16 lanes sharing (lane>>4)
#pragma unroll
    for (int i = 0; i < 2; i++)
#pragma unroll
      for (int r = 0; r < 4; r++) {
        float s = part[i][r];
        s += __shfl_xor(s, 1);
        s += __shfl_xor(s, 2);
        s += __shfl_xor(s, 4);
        s += __shfl_xor(s, 8);
        li[i][r] += s;
      }
    __syncthreads();  // conservative: ensure P writes land before A-frag reads

    // ctx += P[32q x 64k] @ V[64k x 64d]   (k inner, 2 MFMA k-steps)
#pragma unroll
    for (int ks = 0; ks < 2; ++ks) {
      int kq = ks * 32 + (lane >> 4) * 8;
      bf16x8 af[2], bfr[4];
#pragma unroll
      for (int i = 0; i < 2; i++)
        af[i] = *(const bf16x8*)&lP[(w * 32 + i * 16 + (lane & 15)) * 72 + kq];
#pragma unroll
      for (int j = 0; j < 4; j++)
        bfr[j] = *(const bf16x8*)&lV[(j * 16 + (lane & 15)) * 72 + kq];
#pragma unroll
      for (int i = 0; i < 2; i++)
#pragma unroll
        for (int j = 0; j < 4; j++)
          cacc[i][j] =
              __builtin_amdgcn_mfma_f32_16x16x32_bf16(af[i], bfr[j], cacc[i][j], 0, 0, 0);
    }
  }

  // epilogue: divide by row sums, write ctx in [B,M,S,D] layout (col = h*64+d)
#pragma unroll
  for (int i = 0; i < 2; i++)
#pragma unroll
    for (int j = 0; j < 4; j++) {
      long dcol = colbase + j * 16 + (lane & 15);
#pragma unroll
      for (int r = 0; r < 4; r++) {
        long qrow = rowbase + qt * 128 + w * 32 + i * 16 + (lane >> 4) * 4 + r;
        ctx[qrow * 512 + dcol] = f2bf(cacc[i][j][r] / li[i][r]);
      }
    }
}

extern "C" void kernel_launch(void* const* d_in, const int* in_sizes, int n_in,
                              void* d_out, int out_size, void* d_ws, size_t ws_size,
                              hipStream_t stream) {
  (void)in_sizes; (void)n_in; (void)out_size; (void)ws_size;
  const float* x = (const float*)d_in[0];
  const float* Wq = (const float*)d_in[1];
  const float* bq = (const float*)d_in[2];
  const float* Wkv = (const float*)d_in[3];
  const float* bkv = (const float*)d_in[4];
  const float* Wo = (const float*)d_in[5];
  const float* bo = (const float*)d_in[6];

  char* ws = (char*)d_ws;
  unsigned short* x_bf   = (unsigned short*)(ws);                  // 16 MiB
  unsigned short* Wq_bf  = (unsigned short*)(ws + 16777216);       // 512 KiB
  unsigned short* Wkv_bf = (unsigned short*)(ws + 17301504);       // 512 KiB
  unsigned short* Wo_bf  = (unsigned short*)(ws + 17825792);       // 512 KiB
  unsigned short* Q_bf   = (unsigned short*)(ws + 18350080);       // 16 MiB (-> Qn in-place)
  unsigned short* KV_bf  = (unsigned short*)(ws + 35127296);       // 16 MiB (= V)
  unsigned short* Kn_bf  = (unsigned short*)(ws + 51904512);       // 16 MiB
  unsigned short* ctx_bf = (unsigned short*)(ws + 68681728);       // 16 MiB
  // total ws use: 85,458,944 B

  cvt_f32_bf16<<<8192, 256, 0, stream>>>(x, x_bf, 2097152);
  cvt_f32_bf16<<<256, 256, 0, stream>>>(Wq, Wq_bf, 65536);
  cvt_f32_bf16<<<256, 256, 0, stream>>>(Wkv, Wkv_bf, 65536);
  cvt_f32_bf16<<<256, 256, 0, stream>>>(Wo, Wo_bf, 65536);

  dim3 gg(128, 4);  // 16384/128 x 512/128
  gemm_bt<false><<<gg, 256, 0, stream>>>(x_bf, Wq_bf, bq, Q_bf, 512, 512);
  gemm_bt<false><<<gg, 256, 0, stream>>>(x_bf, Wkv_bf, bkv, KV_bf, 512, 512);

  l2norm_heads<<<32768, 256, 0, stream>>>(Q_bf, Q_bf);     // in-place Qn
  l2norm_heads<<<32768, 256, 0, stream>>>(KV_bf, Kn_bf);   // Kn separate (V = KV_bf)

  attn_cos<<<dim3(16, 64), 256, 0, stream>>>(Q_bf, Kn_bf, KV_bf, ctx_bf);

  gemm_bt<true><<<gg, 256, 0, stream>>>(ctx_bf, Wo_bf, bo, d_out, 512, 512);
}

// Round 2
// 281.310 us; speedup vs baseline: 1.5356x; 1.5356x over previous
//
#include <hip/hip_runtime.h>

typedef __attribute__((ext_vector_type(8))) short bf16x8;
typedef __attribute__((ext_vector_type(4))) float f32x4;

__device__ __forceinline__ unsigned short f2bf(float f) {
  union { float f; unsigned int i; } v;
  v.f = f;
  unsigned int r = v.i + 0x7FFFu + ((v.i >> 16) & 1u);  // RNE
  return (unsigned short)(r >> 16);
}

// ---------------- fp32 -> bf16 convert (4 elems/thread) ----------------
__global__ __launch_bounds__(256) void cvt_f32_bf16(
    const float* __restrict__ in, unsigned short* __restrict__ out, int n4) {
  int i = blockIdx.x * 256 + threadIdx.x;
  if (i >= n4) return;
  float4 v = ((const float4*)in)[i];
  ushort4 o;
  o.x = f2bf(v.x);
  o.y = f2bf(v.y);
  o.z = f2bf(v.z);
  o.w = f2bf(v.w);
  ((ushort4*)out)[i] = o;
}

// ---------------- GEMM: C[M,N] = A[M,K] @ Bt[N,K]^T + bias ----------------
// MODE 0: f32 out. MODE 1: bf16 L2-normalized per 64-col head (Qn).
// MODE 2: bf16 raw (out0=KV) + bf16 normalized (out1=Kn).
// Each wave's 64-col span is exactly one head (N=512, 64-aligned), so the
// norm reduce is a 16-lane xor shuffle in the epilogue.
template <int MODE>
__global__ __launch_bounds__(256) void gemm_bt(
    const unsigned short* __restrict__ A, const unsigned short* __restrict__ Bt,
    const float* __restrict__ bias, void* __restrict__ out0,
    unsigned short* __restrict__ out1, int N, int K) {
  __shared__ unsigned short lA[128 * 72];
  __shared__ unsigned short lB[128 * 72];
  const int tid = threadIdx.x;
  const int lane = tid & 63;
  const int quad = lane >> 4, m16 = lane & 15;
  const int w = tid >> 6;
  const int wm = w >> 1, wn = w & 1;
  const long mb = (long)blockIdx.x * 128;
  const long nb = (long)blockIdx.y * 128;
  f32x4 acc[4][4];
#pragma unroll
  for (int i = 0; i < 4; i++)
#pragma unroll
    for (int j = 0; j < 4; j++) acc[i][j] = (f32x4){0.f, 0.f, 0.f, 0.f};

  for (int kb = 0; kb < K; kb += 64) {
    __syncthreads();
#pragma unroll
    for (int c = tid; c < 1024; c += 256) {
      int row = c >> 3, k8 = (c & 7) << 3;
      *(uint4*)&lA[row * 72 + k8] = *(const uint4*)(A + (mb + row) * K + kb + k8);
      *(uint4*)&lB[row * 72 + k8] = *(const uint4*)(Bt + (nb + row) * K + kb + k8);
    }
    __syncthreads();
#pragma unroll
    for (int ks = 0; ks < 64; ks += 32) {
      int kq = ks + quad * 8;
      bf16x8 af[4], bfr[4];
#pragma unroll
      for (int i = 0; i < 4; i++)
        af[i] = *(const bf16x8*)&lA[(wm * 64 + i * 16 + m16) * 72 + kq];
#pragma unroll
      for (int j = 0; j < 4; j++)
        bfr[j] = *(const bf16x8*)&lB[(wn * 64 + j * 16 + m16) * 72 + kq];
#pragma unroll
      for (int i = 0; i < 4; i++)
#pragma unroll
        for (int j = 0; j < 4; j++)
          acc[i][j] =
              __builtin_amdgcn_mfma_f32_16x16x32_bf16(af[i], bfr[j], acc[i][j], 0, 0, 0);
    }
  }
  // C/D layout: col = lane&15, row = quad*4 + r
#pragma unroll
  for (int i = 0; i < 4; i++) {
    long row0 = mb + wm * 64 + i * 16 + quad * 4;
    float bb[4], val[4][4];
#pragma unroll
    for (int j = 0; j < 4; j++) {
      bb[j] = bias[nb + wn * 64 + j * 16 + m16];
#pragma unroll
      for (int r = 0; r < 4; r++) val[j][r] = acc[i][j][r] + bb[j];
    }
    if (MODE == 0) {
#pragma unroll
      for (int j = 0; j < 4; j++) {
        long col = nb + wn * 64 + j * 16 + m16;
#pragma unroll
        for (int r = 0; r < 4; r++) ((float*)out0)[(row0 + r) * N + col] = val[j][r];
      }
    } else {
#pragma unroll
      for (int r = 0; r < 4; r++) {
        float s = val[0][r] * val[0][r] + val[1][r] * val[1][r] +
                  val[2][r] * val[2][r] + val[3][r] * val[3][r];
        s += __shfl_xor(s, 1);
        s += __shfl_xor(s, 2);
        s += __shfl_xor(s, 4);
        s += __shfl_xor(s, 8);
        float inv = 1.0f / fmaxf(sqrtf(s), 1e-12f);
#pragma unroll
        for (int j = 0; j < 4; j++) {
          long col = nb + wn * 64 + j * 16 + m16;
          if (MODE == 1) {
            ((unsigned short*)out0)[(row0 + r) * N + col] = f2bf(val[j][r] * inv);
          } else {
            ((unsigned short*)out0)[(row0 + r) * N + col] = f2bf(val[j][r]);
            out1[(row0 + r) * N + col] = f2bf(val[j][r] * inv);
          }
        }
      }
    }
  }
}

// ---------------- V transpose: KV[s][512] -> Vt[g=64][d=64][s=2048] ----------------
// XOR-swizzled LDS tile (stride 72 + swizzle on d by ((s>>3)&7)<<3): vector
// global I/O both ways, conflict-free LDS both phases.
__global__ __launch_bounds__(256) void transpose_v(
    const unsigned short* __restrict__ KV, unsigned short* __restrict__ Vt) {
  __shared__ unsigned short t[64 * 72];
  const int st = blockIdx.x;  // s-tile 0..31
  const int g = blockIdx.y;   // 0..63
  const int bm = g >> 3, h = g & 7;
  const int tid = threadIdx.x;
#pragma unroll
  for (int p = 0; p < 2; ++p) {
    int c = tid + p * 256;
    int s = c >> 3, d8 = (c & 7) << 3;
    int dsw = d8 ^ (((s >> 3) & 7) << 3);
    *(uint4*)&t[s * 72 + dsw] =
        *(const uint4*)(KV + ((long)bm * 2048 + st * 64 + s) * 512 + h * 64 + d8);
  }
  __syncthreads();
#pragma unroll
  for (int p = 0; p < 2; ++p) {
    int c = tid + p * 256;
    int d = c >> 3, s8 = (c & 7) << 3;
    int swz = (c & 7) << 3;  // = ((s8+j)>>3)&7 << 3 for j<8
    unsigned short v[8];
#pragma unroll
    for (int j = 0; j < 8; ++j) v[j] = t[(s8 + j) * 72 + (d ^ swz)];
    *(uint4*)(Vt + ((long)g * 64 + d) * 2048 + st * 64 + s8) = *(uint4*)v;
  }
}

// ---------------- cosine attention ----------------
// Block: (q-tile 128, group g). 4 waves x 32 q-rows. K-tile 64.
// S^T = Kn @ Q^T (MFMA operand swap): C-layout gives 4 consecutive k per
// lane -> packed b64 P-writes, per-lane scalar li. lP rows are wave-private
// -> no barrier between P write and PV read. Q frags live in registers.
__global__ __launch_bounds__(256, 4) void attn_cos(
    const unsigned short* __restrict__ Qn, const unsigned short* __restrict__ Kn,
    const unsigned short* __restrict__ Vt, unsigned short* __restrict__ ctx) {
  __shared__ unsigned short lK[64 * 72];   // Kn tile [k][d]
  __shared__ unsigned short lVt[64 * 72];  // V^T tile [d][k]
  __shared__ unsigned short lP[128 * 72];  // P [q][k], wave-private rows
  const int qt = blockIdx.x;  // 0..15
  const int g = blockIdx.y;   // 0..63
  const int bm = g >> 3, h = g & 7;
  const int tid = threadIdx.x;
  const int lane = tid & 63;
  const int quad = lane >> 4, m16 = lane & 15;
  const int w = tid >> 6;
  const long rowbase = (long)bm * 2048;
  const int colbase = h * 64;
  const long qrow0 = rowbase + qt * 128 + w * 32;
  const unsigned short* Kbase = Kn + rowbase * 512 + colbase;
  const unsigned short* Vbase = Vt + (long)g * 64 * 2048;

  // Q B-fragments (fixed for all k-tiles): [n=q][d = ks*32 + quad*8 + 0..7]
  bf16x8 qf[2][2];
#pragma unroll
  for (int i = 0; i < 2; i++)
#pragma unroll
    for (int ks = 0; ks < 2; ks++)
      qf[i][ks] = *(const bf16x8*)(Qn + (qrow0 + i * 16 + m16) * 512 + colbase +
                                   ks * 32 + quad * 8);

  f32x4 cacc[2][4];
#pragma unroll
  for (int i = 0; i < 2; i++)
#pragma unroll
    for (int j = 0; j < 4; j++) cacc[i][j] = (f32x4){0.f, 0.f, 0.f, 0.f};
  float li[2] = {0.f, 0.f};

  for (int kt = 0; kt < 32; ++kt) {
    __syncthreads();
#pragma unroll
    for (int p = 0; p < 2; ++p) {
      int c = tid + p * 256;  // 0..511
      int row = c >> 3, e8 = (c & 7) << 3;
      *(uint4*)&lK[row * 72 + e8] = *(const uint4*)(Kbase + (kt * 64 + row) * 512 + e8);
      *(uint4*)&lVt[row * 72 + e8] = *(const uint4*)(Vbase + row * 2048 + kt * 64 + e8);
    }
    __syncthreads();

    // S^T[k][q]: A = Kn frag (m=k), B = Q frag (n=q), contraction d=64
    f32x4 sacc[4][2];
#pragma unroll
    for (int j = 0; j < 4; j++)
#pragma unroll
      for (int i = 0; i < 2; i++) sacc[j][i] = (f32x4){0.f, 0.f, 0.f, 0.f};
#pragma unroll
    for (int ks = 0; ks < 2; ++ks) {
      int dq = ks * 32 + quad * 8;
      bf16x8 kf[4];
#pragma unroll
      for (int j = 0; j < 4; j++)
        kf[j] = *(const bf16x8*)&lK[(j * 16 + m16) * 72 + dq];
#pragma unroll
      for (int j = 0; j < 4; j++)
#pragma unroll
        for (int i = 0; i < 2; i++)
          sacc[j][i] =
              __builtin_amdgcn_mfma_f32_16x16x32_bf16(kf[j], qf[i][ks], sacc[j][i], 0, 0, 0);
    }

    // exp + packed P write + per-lane li. Lane holds q = i*16+m16 (fixed),
    // k = j*16 + quad*4 + r (4 consecutive) -> b64 write.
#pragma unroll
    for (int j = 0; j < 4; j++)
#pragma unroll
      for (int i = 0; i < 2; i++) {
        float p0 = __expf(sacc[j][i][0]);
        float p1 = __expf(sacc[j][i][1]);
        float p2 = __expf(sacc[j][i][2]);
        float p3 = __expf(sacc[j][i][3]);
        li[i] += (p0 + p1) + (p2 + p3);
        unsigned int lo = (unsigned int)f2bf(p0) | ((unsigned int)f2bf(p1) << 16);
        unsigned int hi = (unsigned int)f2bf(p2) | ((unsigned int)f2bf(p3) << 16);
        uint2 pk = make_uint2(lo, hi);
        *(uint2*)&lP[(w * 32 + i * 16 + m16) * 72 + j * 16 + quad * 4] = pk;
      }

    // PV: ctx[q][d] += P @ V, contraction k=64 (wave-private lP, no barrier)
#pragma unroll
    for (int ks = 0; ks < 2; ++ks) {
      int kq = ks * 32 + quad * 8;
      bf16x8 pf[2], vf[4];
#pragma unroll
      for (int i = 0; i < 2; i++)
        pf[i] = *(const bf16x8*)&lP[(w * 32 + i * 16 + m16) * 72 + kq];
#pragma unroll
      for (int j = 0; j < 4; j++)
        vf[j] = *(const bf16x8*)&lVt[(j * 16 + m16) * 72 + kq];
#pragma unroll
      for (int i = 0; i < 2; i++)
#pragma unroll
        for (int j = 0; j < 4; j++)
          cacc[i][j] =
              __builtin_amdgcn_mfma_f32_16x16x32_bf16(pf[i], vf[j], cacc[i][j], 0, 0, 0);
    }
  }

  // reduce li across quads (lanes sharing m16)
#pragma unroll
  for (int i = 0; i < 2; i++) {
    li[i] += __shfl_xor(li[i], 16);
    li[i] += __shfl_xor(li[i], 32);
  }
  // epilogue: lane needs li for row q% = quad*4+r -> shfl from lane quad*4+r
  float linv[2][4];
#pragma unroll
  for (int i = 0; i < 2; i++)
#pragma unroll
    for (int r = 0; r < 4; r++) linv[i][r] = 1.0f / __shfl(li[i], quad * 4 + r);
#pragma unroll
  for (int i = 0; i < 2; i++)
#pragma unroll
    for (int j = 0; j < 4; j++) {
      long dcol = colbase + j * 16 + m16;
#pragma unroll
      for (int r = 0; r < 4; r++) {
        long qrow = qrow0 + i * 16 + quad * 4 + r;
        ctx[qrow * 512 + dcol] = f2bf(cacc[i][j][r] * linv[i][r]);
      }
    }
}

extern "C" void kernel_launch(void* const* d_in, const int* in_sizes, int n_in,
                              void* d_out, int out_size, void* d_ws, size_t ws_size,
                              hipStream_t stream) {
  (void)in_sizes; (void)n_in; (void)out_size; (void)ws_size;
  const float* x = (const float*)d_in[0];
  const float* Wq = (const float*)d_in[1];
  const float* bq = (const float*)d_in[2];
  const float* Wkv = (const float*)d_in[3];
  const float* bkv = (const float*)d_in[4];
  const float* Wo = (const float*)d_in[5];
  const float* bo = (const float*)d_in[6];

  char* ws = (char*)d_ws;
  unsigned short* x_bf   = (unsigned short*)(ws);             // 16 MiB (reused as ctx)
  unsigned short* Wq_bf  = (unsigned short*)(ws + 16777216);  // 512 KiB
  unsigned short* Wkv_bf = (unsigned short*)(ws + 17301504);  // 512 KiB
  unsigned short* Wo_bf  = (unsigned short*)(ws + 17825792);  // 512 KiB
  unsigned short* Qn_bf  = (unsigned short*)(ws + 18350080);  // 16 MiB
  unsigned short* KV_bf  = (unsigned short*)(ws + 35127296);  // 16 MiB (= V)
  unsigned short* Kn_bf  = (unsigned short*)(ws + 51904512);  // 16 MiB
  unsigned short* Vt_bf  = (unsigned short*)(ws + 68681728);  // 16 MiB
  unsigned short* ctx_bf = x_bf;  // x dead after gemm_kv

  cvt_f32_bf16<<<8192, 256, 0, stream>>>(x, x_bf, 2097152);
  cvt_f32_bf16<<<256, 256, 0, stream>>>(Wq, Wq_bf, 65536);
  cvt_f32_bf16<<<256, 256, 0, stream>>>(Wkv, Wkv_bf, 65536);
  cvt_f32_bf16<<<256, 256, 0, stream>>>(Wo, Wo_bf, 65536);

  dim3 gg(128, 4);  // 16384/128 x 512/128
  gemm_bt<1><<<gg, 256, 0, stream>>>(x_bf, Wq_bf, bq, Qn_bf, nullptr, 512, 512);
  gemm_bt<2><<<gg, 256, 0, stream>>>(x_bf, Wkv_bf, bkv, KV_bf, Kn_bf, 512, 512);

  transpose_v<<<dim3(32, 64), 256, 0, stream>>>(KV_bf, Vt_bf);

  attn_cos<<<dim3(16, 64), 256, 0, stream>>>(Qn_bf, Kn_bf, Vt_bf, ctx_bf);

  gemm_bt<0><<<gg, 256, 0, stream>>>(ctx_bf, Wo_bf, bo, d_out, nullptr, 512, 512);
}